// Round 1
// baseline (539.481 us; speedup 1.0000x reference)
//
#include <hip/hip_runtime.h>

#define BB 4
#define HH 8
#define LL 8192
#define NN (BB*LL)
#define DDIM 32
#define MM 128
#define NR (NN*HH)          // 262144 rows (n,h)

// ws layout (float offsets)
#define QF_OFF   0                       // NR*32 pre-scaled feature rows
#define DIAG_OFF (NR*DDIM)               // NR
#define RMAX_OFF (DIAG_OFF + NR)         // NR
#define KSUM_OFF (RMAX_OFF + NR)         // B*H*M
#define CTX_OFF  (KSUM_OFF + BB*HH*MM)   // B*H*8*M*4
#define GMAX_OFF (CTX_OFF + BB*HH*8*MM*4)
#define ZERO_FLOATS (GMAX_OFF + 1 - KSUM_OFF)

#define DN 0.42044820762685725f          // 32^-0.25
#define RATIO 0.08838834764831845f       // 128^-0.5
#define EPSF 1e-4f

// ---------------- kernel 1: features, dd row-max, diag, global max ----------
__global__ __launch_bounds__(256) void k_prep(const float* __restrict__ k0,
                                              const float* __restrict__ k1,
                                              const float* __restrict__ w,
                                              float* __restrict__ ws) {
    __shared__ float wst[MM*DDIM];
    __shared__ float qs[2][DDIM];
    __shared__ float wmax[4];
    __shared__ float bred[4];
    const int tid = threadIdx.x;
    for (int i = tid; i < MM*DDIM; i += 256) wst[i] = w[i];
    __syncthreads();
    const int m = tid & 127;
    float wreg[DDIM];
#pragma unroll
    for (int d = 0; d < DDIM; ++d) wreg[d] = wst[m*DDIM + d];
    const int sub = tid >> 7;
    float blockmax = -3.4e38f;
    float* qf   = ws + QF_OFF;
    float* diag = ws + DIAG_OFF;
    float* rmax = ws + RMAX_OFF;
    for (int pair = blockIdx.x; pair < NR/2; pair += gridDim.x) {
        const int r = pair*2 + sub;
        const int n = r >> 3, h = r & 7;
        __syncthreads();
        if ((tid & 127) < DDIM) {
            const int d = tid & 127;
            const int base = n*64 + h*8;
            const float v = (d < 8) ? k0[base + d] : k1[base*3 + (d - 8)];
            qs[sub][d] = v * DN;
        }
        __syncthreads();
        float dd = 0.f, ss = 0.f;
#pragma unroll
        for (int d = 0; d < DDIM; ++d) {
            const float q = qs[sub][d];
            dd = fmaf(q, wreg[d], dd);
            ss = fmaf(q, q, ss);
        }
        float mx = dd;
#pragma unroll
        for (int off = 32; off; off >>= 1) mx = fmaxf(mx, __shfl_xor(mx, off, 64));
        if ((tid & 63) == 0) wmax[tid >> 6] = mx;
        __syncthreads();
        const float rm = fmaxf(wmax[sub*2], wmax[sub*2 + 1]);
        if ((tid & 127) == 0) { rmax[r] = rm; diag[r] = 0.5f * ss; }
        if ((tid & 127) < DDIM) qf[r*DDIM + (tid & 127)] = qs[sub][tid & 127];
        blockmax = fmaxf(blockmax, rm);
    }
    float bm = blockmax;
#pragma unroll
    for (int off = 32; off; off >>= 1) bm = fmaxf(bm, __shfl_xor(bm, off, 64));
    if ((tid & 63) == 0) bred[tid >> 6] = bm;
    __syncthreads();
    if (tid == 0) {
        const float g = fmaxf(fmaxf(bred[0], bred[1]), fmaxf(bred[2], bred[3]));
        unsigned u = __float_as_uint(g);
        u = (u & 0x80000000u) ? ~u : (u | 0x80000000u);
        atomicMax((unsigned*)(ws + GMAX_OFF), u);
    }
}

// ---------------- kernel 2: Kp on the fly -> ctx + Ksum ---------------------
__global__ __launch_bounds__(256) void k_ctx(const float* __restrict__ v0,
                                             const float* __restrict__ v1,
                                             const float* __restrict__ w,
                                             float* __restrict__ ws) {
    __shared__ float wst[MM*DDIM];
    __shared__ float sv[8][64];     // per l: [0:32)=qs row, [32:40)=v0, [40:64)=v1
    __shared__ float sdiag[8];
    const int tid = threadIdx.x;
    for (int i = tid; i < MM*DDIM; i += 256) wst[i] = w[i];
    __syncthreads();
    const int m = tid & 127, half = tid >> 7;
    float wreg[DDIM];
#pragma unroll
    for (int d = 0; d < DDIM; ++d) wreg[d] = wst[m*DDIM + d];
    const int bh = blockIdx.x >> 5;      // 0..31
    const int chunk = blockIdx.x & 31;   // 0..31
    const int b = bh >> 3, h = bh & 7;
    const int l0 = chunk * 256;
    const unsigned gu = *((const unsigned*)(ws + GMAX_OFF));
    const float gm = (gu & 0x80000000u) ? __uint_as_float(gu & 0x7fffffffu)
                                        : __uint_as_float(~gu);
    const float* qf   = ws + QF_OFF;
    const float* diag = ws + DIAG_OFF;
    float acc[16];
#pragma unroll
    for (int i = 0; i < 16; ++i) acc[i] = 0.f;
    float ksum_acc = 0.f;
    for (int lb = 0; lb < 256; lb += 8) {
        __syncthreads();
        for (int idx = tid; idx < 512; idx += 256) {
            const int lp = idx >> 6, f = idx & 63;
            const int l = l0 + lb + lp;
            const int n = b*LL + l;
            float v;
            if (f < 32)      v = qf[(n*8 + h)*DDIM + f];
            else if (f < 40) v = v0[n*64 + h*8 + (f - 32)];
            else             v = v1[(n*64 + h*8)*3 + (f - 40)];
            sv[lp][f] = v;
        }
        if (tid < 8) {
            const int l = l0 + lb + tid;
            sdiag[tid] = diag[(b*LL + l)*8 + h];
        }
        __syncthreads();
#pragma unroll
        for (int lp = 0; lp < 8; ++lp) {
            float dd = 0.f;
#pragma unroll
            for (int d = 0; d < DDIM; ++d) dd = fmaf(sv[lp][d], wreg[d], dd);
            const float kp = RATIO * (__expf(dd - sdiag[lp] - gm) + EPSF);
            ksum_acc += kp;
#pragma unroll
            for (int cc = 0; cc < 4; ++cc) {
                const int c = half*4 + cc;
                acc[cc*4 + 0] = fmaf(kp, sv[lp][32 + c],       acc[cc*4 + 0]);
                acc[cc*4 + 1] = fmaf(kp, sv[lp][40 + c*3 + 0], acc[cc*4 + 1]);
                acc[cc*4 + 2] = fmaf(kp, sv[lp][40 + c*3 + 1], acc[cc*4 + 2]);
                acc[cc*4 + 3] = fmaf(kp, sv[lp][40 + c*3 + 2], acc[cc*4 + 3]);
            }
        }
    }
    float* ctx  = ws + CTX_OFF;
    float* ksum = ws + KSUM_OFF;
#pragma unroll
    for (int cc = 0; cc < 4; ++cc) {
        const int c = half*4 + cc;
#pragma unroll
        for (int j = 0; j < 4; ++j)
            atomicAdd(&ctx[((bh*8 + c)*MM + m)*4 + j], acc[cc*4 + j]);
    }
    if (half == 0) atomicAdd(&ksum[bh*MM + m], ksum_acc);
}

// ---------------- kernel 3: Qp, D_inv, readout ------------------------------
__global__ __launch_bounds__(256) void k_out(const float* __restrict__ w,
                                             const float* __restrict__ ws,
                                             float* __restrict__ out) {
    __shared__ float buf[8*524];     // padded ctx slice (also stages w first)
    __shared__ float ksl[MM];
    __shared__ float qpl[2][MM];
    __shared__ float red[256];
    __shared__ float wm[4];
    __shared__ float qrow[2][DDIM];
    const int tid = threadIdx.x;
    for (int i = tid; i < MM*DDIM; i += 256) buf[i] = w[i];
    __syncthreads();
    const int m = tid & 127;
    const int sub = tid >> 7;
    float wreg[DDIM];
#pragma unroll
    for (int d = 0; d < DDIM; ++d) wreg[d] = buf[m*DDIM + d];
    __syncthreads();
    const int bh = blockIdx.x >> 6;   // 32 bh x 64 blocks
    const int blk = blockIdx.x & 63;
    const int b = bh >> 3, h = bh & 7;
    const float* ctx = ws + CTX_OFF;
    for (int g = tid; g < 4096; g += 256) {
        const int c = g >> 9, rem = g & 511;
        buf[c*524 + rem] = ctx[bh*4096 + g];   // pad stride 524 -> conflict-free
    }
    if (tid < MM) ksl[tid] = ws[KSUM_OFF + bh*MM + tid];
    __syncthreads();
    const float* qf   = ws + QF_OFF;
    const float* diag = ws + DIAG_OFF;
    const float* rmax = ws + RMAX_OFF;
    const int l0 = blk * 128;
    const int o = tid & 31, qq = (tid >> 5) & 3;
    const int oc = o >> 2, oj = o & 3;
    for (int it = 0; it < 64; ++it) {
        const int l = l0 + it*2 + sub;
        const int n = b*LL + l;
        const int r = n*8 + h;
        __syncthreads();
        if ((tid & 127) < DDIM) qrow[sub][tid & 127] = qf[r*DDIM + (tid & 127)];
        __syncthreads();
        float dd = 0.f;
#pragma unroll
        for (int d = 0; d < DDIM; ++d) dd = fmaf(qrow[sub][d], wreg[d], dd);
        const float qp = RATIO * (__expf(dd - diag[r] - rmax[r]) + EPSF);
        qpl[sub][m] = qp;
        float p = qp * ksl[m];
#pragma unroll
        for (int off = 32; off; off >>= 1) p += __shfl_xor(p, off, 64);
        if ((tid & 63) == 0) wm[tid >> 6] = p;
        __syncthreads();
        const float dv = 1.f / (wm[sub*2] + wm[sub*2 + 1]);
        float s = 0.f;
#pragma unroll
        for (int i = 0; i < 32; ++i) {
            const int mm2 = qq*32 + i;
            s = fmaf(qpl[sub][mm2], buf[oc*524 + mm2*4 + oj], s);
        }
        red[tid] = s;
        __syncthreads();
        if ((tid & 127) < 32) {
            const float tot = red[sub*128 + o] + red[sub*128 + 32 + o]
                            + red[sub*128 + 64 + o] + red[sub*128 + 96 + o];
            const float val = tot * dv;
            const int base = n*64 + h*8 + oc;
            if (oj == 0) out[base] = val;
            else         out[NN*64 + base*3 + (oj - 1)] = val;
        }
    }
}

extern "C" void kernel_launch(void* const* d_in, const int* in_sizes, int n_in,
                              void* d_out, int out_size, void* d_ws, size_t ws_size,
                              hipStream_t stream) {
    const float* v0 = (const float*)d_in[0];
    const float* v1 = (const float*)d_in[1];
    const float* k0 = (const float*)d_in[2];
    const float* k1 = (const float*)d_in[3];
    const float* w  = (const float*)d_in[6];
    float* out = (float*)d_out;
    float* ws  = (float*)d_ws;
    hipMemsetAsync(ws + KSUM_OFF, 0, (size_t)ZERO_FLOATS*sizeof(float), stream);
    k_prep<<<2048, 256, 0, stream>>>(k0, k1, w, ws);
    k_ctx <<<1024, 256, 0, stream>>>(v0, v1, w, ws);
    k_out <<<2048, 256, 0, stream>>>(w, ws, out);
}

// Round 2
// 440.124 us; speedup vs baseline: 1.2257x; 1.2257x over previous
//
#include <hip/hip_runtime.h>

#define BB 4
#define HH 8
#define LL 8192
#define NN (BB*LL)
#define DDIM 32
#define MM 128
#define NR (NN*HH)          // 262144 rows (n,h)

// ws layout (float offsets)
#define QF_OFF   0                       // NR*32 pre-scaled feature rows
#define DIAG_OFF (NR*DDIM)               // NR
#define RMAX_OFF (DIAG_OFF + NR)         // NR
#define KSUM_OFF (RMAX_OFF + NR)         // B*H*M
#define CTX_OFF  (KSUM_OFF + BB*HH*MM)   // B*H*8*M*4
#define GMAX_OFF (CTX_OFF + BB*HH*8*MM*4)
#define ZERO_FLOATS (GMAX_OFF + 1 - KSUM_OFF)

#define DN 0.42044820762685725f          // 32^-0.25
#define RATIO 0.08838834764831845f       // 128^-0.5
#define EPSF 1e-4f

// ---------------- kernel 1: features, dd row-max, diag, global max ----------
__global__ __launch_bounds__(256) void k_prep(const float* __restrict__ k0,
                                              const float* __restrict__ k1,
                                              const float* __restrict__ w,
                                              float* __restrict__ ws) {
    __shared__ float wst[MM*DDIM];
    __shared__ float feat[16][36];
    __shared__ float ddl[16][132];
    __shared__ float bred[4];
    const int tid = threadIdx.x;
    for (int i = tid; i < MM*DDIM; i += 256) wst[i] = w[i];
    __syncthreads();
    const int m = tid & 127, half = tid >> 7;
    float wreg[DDIM];
#pragma unroll
    for (int d = 0; d < DDIM; ++d) wreg[d] = wst[m*DDIM + d];
    float* qf   = ws + QF_OFF;
    float* diag = ws + DIAG_OFF;
    float* rmax = ws + RMAX_OFF;
    float blockmax = -3.4e38f;
    for (int t16 = 0; t16 < 8; ++t16) {
        const int rbase = blockIdx.x*128 + t16*16;   // 16 rows = 2 n x 8 h
        const int n0 = rbase >> 3;
        __syncthreads();
        // stage features (scaled by DN): k0 128 floats + k1 384 floats
        for (int e = tid; e < 512; e += 256) {
            if (e < 128) {
                const int ln = e >> 6, rem = e & 63;
                feat[ln*8 + (rem >> 3)][rem & 7] = k0[n0*64 + e] * DN;
            } else {
                const int e2 = e - 128;
                const int ln = (e2 >= 192) ? 1 : 0;
                const int rem = e2 - ln*192;
                const int h2 = rem / 24, dd2 = rem - h2*24;
                feat[ln*8 + h2][8 + dd2] = k1[n0*192 + e2] * DN;
            }
        }
        __syncthreads();
        // qf store (coalesced)
        for (int i = tid; i < 512; i += 256)
            qf[rbase*32 + i] = feat[i >> 5][i & 31];
        // diag: 64 threads, 4 per row
        if (tid < 64) {
            const int row = tid >> 2, dq = tid & 3;
            const float4 a = *(const float4*)&feat[row][dq*8];
            const float4 b = *(const float4*)&feat[row][dq*8 + 4];
            float ss = a.x*a.x + a.y*a.y + a.z*a.z + a.w*a.w
                     + b.x*b.x + b.y*b.y + b.z*b.z + b.w*b.w;
            ss += __shfl_xor(ss, 1);
            ss += __shfl_xor(ss, 2);
            if (dq == 0) diag[rbase + row] = 0.5f * ss;
        }
        // dd for the 8 rows of this half
#pragma unroll
        for (int r8 = 0; r8 < 8; ++r8) {
            const int row = half*8 + r8;
            const float4* f4 = (const float4*)&feat[row][0];
            float dd = 0.f;
#pragma unroll
            for (int q8 = 0; q8 < 8; ++q8) {
                const float4 qv = f4[q8];
                dd = fmaf(qv.x, wreg[q8*4+0], dd);
                dd = fmaf(qv.y, wreg[q8*4+1], dd);
                dd = fmaf(qv.z, wreg[q8*4+2], dd);
                dd = fmaf(qv.w, wreg[q8*4+3], dd);
            }
            ddl[row][m] = dd;
        }
        __syncthreads();
        // row-max over m: 128 threads, 8 per row
        if (tid < 128) {
            const int row = tid >> 3, mo = tid & 7;
            float mx = -3.4e38f;
#pragma unroll
            for (int q = 0; q < 4; ++q) {
                const float4 v = *(const float4*)&ddl[row][mo*16 + q*4];
                mx = fmaxf(mx, fmaxf(fmaxf(v.x, v.y), fmaxf(v.z, v.w)));
            }
            mx = fmaxf(mx, __shfl_xor(mx, 1));
            mx = fmaxf(mx, __shfl_xor(mx, 2));
            mx = fmaxf(mx, __shfl_xor(mx, 4));
            if (mo == 0) rmax[rbase + row] = mx;
            blockmax = fmaxf(blockmax, mx);
        }
    }
    __syncthreads();
    float bm = blockmax;
#pragma unroll
    for (int off = 32; off; off >>= 1) bm = fmaxf(bm, __shfl_xor(bm, off, 64));
    if ((tid & 63) == 0) bred[tid >> 6] = bm;
    __syncthreads();
    if (tid == 0) {
        const float g = fmaxf(fmaxf(bred[0], bred[1]), fmaxf(bred[2], bred[3]));
        unsigned u = __float_as_uint(g);
        u = (u & 0x80000000u) ? ~u : (u | 0x80000000u);
        atomicMax((unsigned*)(ws + GMAX_OFF), u);
    }
}

// ---------------- kernel 2: Kp on the fly -> ctx + Ksum ---------------------
__global__ __launch_bounds__(256) void k_ctx(const float* __restrict__ v0,
                                             const float* __restrict__ v1,
                                             const float* __restrict__ w,
                                             float* __restrict__ ws) {
    __shared__ float wst[MM*DDIM];
    __shared__ float sv[16][64];   // per row: [0:32) feats, [32:64) v packed per-c float4
    __shared__ float sdiag[16];
    const int tid = threadIdx.x;
    for (int i = tid; i < MM*DDIM; i += 256) wst[i] = w[i];
    __syncthreads();
    const int m = tid & 127, half = tid >> 7;
    float wreg[DDIM];
#pragma unroll
    for (int d = 0; d < DDIM; ++d) wreg[d] = wst[m*DDIM + d];
    const int bh = blockIdx.x >> 5;
    const int chunk = blockIdx.x & 31;
    const int b = bh >> 3, h = bh & 7;
    const unsigned gu = *((const unsigned*)(ws + GMAX_OFF));
    const float gm = (gu & 0x80000000u) ? __uint_as_float(gu & 0x7fffffffu)
                                        : __uint_as_float(~gu);
    const float* qf   = ws + QF_OFF;
    const float* diag = ws + DIAG_OFF;
    float acc[16];
#pragma unroll
    for (int i = 0; i < 16; ++i) acc[i] = 0.f;
    float ksum_acc = 0.f;
    for (int batch = 0; batch < 16; ++batch) {
        const int nb0 = b*LL + chunk*256 + batch*16;
        __syncthreads();
#pragma unroll
        for (int p = 0; p < 4; ++p) {
            const int i = tid + p*256;
            if (i < 512) {
                const int lr = i >> 5, d = i & 31;
                sv[lr][d] = qf[(nb0 + lr)*256 + h*32 + d];
            } else if (i < 640) {
                const int j = i - 512, lr = j >> 3, c = j & 7;
                sv[lr][32 + c*4] = v0[(nb0 + lr)*64 + h*8 + c];
            } else {
                const int j = i - 640;
                const int lr = j / 24, rem = j - lr*24;
                const int c = rem / 3, jj = rem - c*3;
                sv[lr][32 + c*4 + 1 + jj] = v1[(nb0 + lr)*192 + h*24 + rem];
            }
        }
        if (tid < 16) sdiag[tid] = diag[(nb0 + tid)*8 + h];
        __syncthreads();
#pragma unroll 4
        for (int lp = 0; lp < 16; ++lp) {
            const float4* f4 = (const float4*)&sv[lp][0];
            float dd = 0.f;
#pragma unroll
            for (int q8 = 0; q8 < 8; ++q8) {
                const float4 qv = f4[q8];
                dd = fmaf(qv.x, wreg[q8*4+0], dd);
                dd = fmaf(qv.y, wreg[q8*4+1], dd);
                dd = fmaf(qv.z, wreg[q8*4+2], dd);
                dd = fmaf(qv.w, wreg[q8*4+3], dd);
            }
            const float kp = RATIO * (__expf(dd - sdiag[lp] - gm) + EPSF);
            ksum_acc += kp;
            const float4* vv = (const float4*)&sv[lp][32];
#pragma unroll
            for (int cc = 0; cc < 4; ++cc) {
                const float4 vq = vv[half*4 + cc];
                acc[cc*4+0] = fmaf(kp, vq.x, acc[cc*4+0]);
                acc[cc*4+1] = fmaf(kp, vq.y, acc[cc*4+1]);
                acc[cc*4+2] = fmaf(kp, vq.z, acc[cc*4+2]);
                acc[cc*4+3] = fmaf(kp, vq.w, acc[cc*4+3]);
            }
        }
    }
    float* ctx  = ws + CTX_OFF;
    float* ksum = ws + KSUM_OFF;
#pragma unroll
    for (int cc = 0; cc < 4; ++cc) {
        const int c = half*4 + cc;
#pragma unroll
        for (int j = 0; j < 4; ++j)
            atomicAdd(&ctx[((bh*8 + c)*MM + m)*4 + j], acc[cc*4 + j]);
    }
    if (half == 0) atomicAdd(&ksum[bh*MM + m], ksum_acc);
}

// ---------------- kernel 3: Qp, D_inv, readout ------------------------------
__global__ __launch_bounds__(256) void k_out(const float* __restrict__ w,
                                             const float* __restrict__ ws,
                                             float* __restrict__ out) {
    __shared__ float ctx_s[8*516];   // padded ctx (also stages w first)
    __shared__ float qpT[128*68];    // qp transposed [m][row], pad 68
    __shared__ float ksl[MM];
    __shared__ float dinv[64];
    const int tid = threadIdx.x;
    for (int i = tid; i < MM*DDIM; i += 256) ctx_s[i] = w[i];
    __syncthreads();
    const int m = tid & 127, half = tid >> 7;
    float wreg[DDIM];
#pragma unroll
    for (int d = 0; d < DDIM; ++d) wreg[d] = ctx_s[m*DDIM + d];
    __syncthreads();
    const int bh = blockIdx.x >> 6, blk = blockIdx.x & 63;
    const int b = bh >> 3, h = bh & 7;
    const float* ctxg = ws + CTX_OFF + bh*4096;
    for (int g = tid; g < 4096; g += 256) {
        const int c = g >> 9, mm2 = (g >> 2) & 127, j = g & 3;
        ctx_s[c*516 + mm2*4 + j] = ctxg[g];
    }
    if (tid < MM) ksl[tid] = ws[KSUM_OFF + bh*MM + tid];
    const float* diag = ws + DIAG_OFF;
    const float* rmax = ws + RMAX_OFF;
    for (int tile = 0; tile < 2; ++tile) {
        const int lbase = blk*128 + tile*64;
        __syncthreads();
        // ---- phase A: Qp for 64 rows -> qpT ----
#pragma unroll
        for (int r4 = 0; r4 < 8; ++r4) {
            float q4[4];
#pragma unroll
            for (int k = 0; k < 4; ++k) {
                const int lr = half*32 + r4*4 + k;
                const int r = (b*LL + lbase + lr)*8 + h;
                const float4* qf4 = (const float4*)(ws + (size_t)r*32);
                float dd = 0.f;
#pragma unroll
                for (int q8 = 0; q8 < 8; ++q8) {
                    const float4 qv = qf4[q8];
                    dd = fmaf(qv.x, wreg[q8*4+0], dd);
                    dd = fmaf(qv.y, wreg[q8*4+1], dd);
                    dd = fmaf(qv.z, wreg[q8*4+2], dd);
                    dd = fmaf(qv.w, wreg[q8*4+3], dd);
                }
                q4[k] = RATIO * (__expf(dd - diag[r] - rmax[r]) + EPSF);
            }
            *(float4*)&qpT[m*68 + half*32 + r4*4] = make_float4(q4[0], q4[1], q4[2], q4[3]);
        }
        __syncthreads();
        // ---- phase B: D_inv per row ----
        {
            const int row = tid >> 2, mq = tid & 3;
            float s = 0.f;
#pragma unroll
            for (int i = 0; i < 32; ++i) {
                const int mm2 = mq*32 + i;
                s = fmaf(qpT[mm2*68 + row], ksl[mm2], s);
            }
            s += __shfl_xor(s, 1);
            s += __shfl_xor(s, 2);
            if (mq == 0) dinv[row] = 1.f / s;
        }
        __syncthreads();
        // ---- phase C: out = (qp . ctx) * dinv ----
        {
            const int c = tid & 7, mh = (tid >> 3) & 1, rg = tid >> 4;
            float4 a0 = {0,0,0,0}, a1 = {0,0,0,0}, a2 = {0,0,0,0}, a3 = {0,0,0,0};
            const float4* cx = (const float4*)&ctx_s[c*516];
            const int mstart = mh*64;
#pragma unroll 8
            for (int i = 0; i < 64; ++i) {
                const int mm2 = mstart + i;
                const float4 cv = cx[mm2];
                const float4 qv = *(const float4*)&qpT[mm2*68 + rg*4];
                a0.x = fmaf(qv.x, cv.x, a0.x); a0.y = fmaf(qv.x, cv.y, a0.y);
                a0.z = fmaf(qv.x, cv.z, a0.z); a0.w = fmaf(qv.x, cv.w, a0.w);
                a1.x = fmaf(qv.y, cv.x, a1.x); a1.y = fmaf(qv.y, cv.y, a1.y);
                a1.z = fmaf(qv.y, cv.z, a1.z); a1.w = fmaf(qv.y, cv.w, a1.w);
                a2.x = fmaf(qv.z, cv.x, a2.x); a2.y = fmaf(qv.z, cv.y, a2.y);
                a2.z = fmaf(qv.z, cv.z, a2.z); a2.w = fmaf(qv.z, cv.w, a2.w);
                a3.x = fmaf(qv.w, cv.x, a3.x); a3.y = fmaf(qv.w, cv.y, a3.y);
                a3.z = fmaf(qv.w, cv.z, a3.z); a3.w = fmaf(qv.w, cv.w, a3.w);
            }
            // combine the two m-halves (partner = tid^8)
            a0.x += __shfl_xor(a0.x, 8); a0.y += __shfl_xor(a0.y, 8);
            a0.z += __shfl_xor(a0.z, 8); a0.w += __shfl_xor(a0.w, 8);
            a1.x += __shfl_xor(a1.x, 8); a1.y += __shfl_xor(a1.y, 8);
            a1.z += __shfl_xor(a1.z, 8); a1.w += __shfl_xor(a1.w, 8);
            a2.x += __shfl_xor(a2.x, 8); a2.y += __shfl_xor(a2.y, 8);
            a2.z += __shfl_xor(a2.z, 8); a2.w += __shfl_xor(a2.w, 8);
            a3.x += __shfl_xor(a3.x, 8); a3.y += __shfl_xor(a3.y, 8);
            a3.z += __shfl_xor(a3.z, 8); a3.w += __shfl_xor(a3.w, 8);
            const float4 s0 = mh ? a2 : a0;
            const float4 s1 = mh ? a3 : a1;
            const int lr0 = rg*4 + mh*2;
#pragma unroll
            for (int k = 0; k < 2; ++k) {
                const float4 sv4 = k ? s1 : s0;
                const int lr = lr0 + k;
                const float dv = dinv[lr];
                const int n = b*LL + lbase + lr;
                const int base = n*64 + h*8 + c;
                out[base] = sv4.x * dv;
                float* o1 = out + NN*64 + base*3;
                o1[0] = sv4.y * dv;
                o1[1] = sv4.z * dv;
                o1[2] = sv4.w * dv;
            }
        }
    }
}

extern "C" void kernel_launch(void* const* d_in, const int* in_sizes, int n_in,
                              void* d_out, int out_size, void* d_ws, size_t ws_size,
                              hipStream_t stream) {
    const float* v0 = (const float*)d_in[0];
    const float* v1 = (const float*)d_in[1];
    const float* k0 = (const float*)d_in[2];
    const float* k1 = (const float*)d_in[3];
    const float* w  = (const float*)d_in[6];
    float* out = (float*)d_out;
    float* ws  = (float*)d_ws;
    hipMemsetAsync(ws + KSUM_OFF, 0, (size_t)ZERO_FLOATS*sizeof(float), stream);
    k_prep<<<2048, 256, 0, stream>>>(k0, k1, w, ws);
    k_ctx <<<1024, 256, 0, stream>>>(v0, v1, w, ws);
    k_out <<<2048, 256, 0, stream>>>(w, ws, out);
}

// Round 4
// 416.371 us; speedup vs baseline: 1.2957x; 1.0570x over previous
//
#include <hip/hip_runtime.h>

#define BB 4
#define HH 8
#define LL 8192
#define NN (BB*LL)
#define DDIM 32
#define MM 128
#define NR (NN*HH)          // 262144 (n,h) rows

// ws layout (float offsets)
#define CTXR_OFF 0                          // 32*8*128*4 = 131072
#define KSUMR_OFF (CTXR_OFF + 32*8*MM*4)    // 4096
#define VSUM_OFF  (KSUMR_OFF + 32*MM)       // 1024
#define GMAX_OFF  (VSUM_OFF + 32*32)        // 1
#define RMAX_OFF  (GMAX_OFF + 1)            // NR
#define DIAG_OFF  (RMAX_OFF + NR)           // NR
#define ZERO_FLOATS (GMAX_OFF + 1)

#define DN 0.42044820762685725f             // 32^-0.25
#define RATIO 0.08838834764831845f          // 128^-0.5
#define EPSF 1e-4f

// ------- k1: fused features + dd + rowmax/diag + exp(dd-diag)*v accumulation
__global__ __launch_bounds__(256) void k_ctx1(const float* __restrict__ kk0,
                                              const float* __restrict__ kk1,
                                              const float* __restrict__ v0,
                                              const float* __restrict__ v1,
                                              const float* __restrict__ w,
                                              float* __restrict__ ws) {
    __shared__ float sv[16][64];    // [0:32) feats*DN, [32:64) v packed per-c float4
    __shared__ float ddl[16][132];
    __shared__ float sdiag[16];
    __shared__ float bred[4];
    const int tid = threadIdx.x;
    const int m = tid & 127, half = tid >> 7;
    float wreg[DDIM];
    {
        const float4* w4 = (const float4*)(w + m*DDIM);
#pragma unroll
        for (int q = 0; q < 8; ++q) {
            const float4 t = w4[q];
            wreg[q*4+0]=t.x; wreg[q*4+1]=t.y; wreg[q*4+2]=t.z; wreg[q*4+3]=t.w;
        }
    }
    const int bh = blockIdx.x >> 5, chunk = blockIdx.x & 31;
    const int b = bh >> 3, h = bh & 7;
    float acc[16];
#pragma unroll
    for (int i = 0; i < 16; ++i) acc[i] = 0.f;
    float ksum_acc = 0.f, vsum_acc = 0.f;
    float blockmax = -3.4e38f;
    float* rmaxg = ws + RMAX_OFF;
    float* diagg = ws + DIAG_OFF;
    for (int s = 0; s < 16; ++s) {
        const int nb0 = b*LL + chunk*256 + s*16;
        __syncthreads();
        // stage 16 rows: feats (k0 8 + k1 24, scaled) and v (v0 1 + v1 3, per-c float4)
#pragma unroll
        for (int p = 0; p < 4; ++p) {
            const int i = tid + p*256;
            int lr, off; float val;
            if (i < 128)      { lr = i >> 3; off = i & 7;
                                val = kk0[(nb0+lr)*64 + h*8 + off] * DN; }
            else if (i < 512) { const int j = i - 128; lr = j/24; const int d2 = j - lr*24;
                                off = 8 + d2; val = kk1[(nb0+lr)*192 + h*24 + d2] * DN; }
            else if (i < 640) { const int j = i - 512; lr = j >> 3; const int c = j & 7;
                                off = 32 + c*4; val = v0[(nb0+lr)*64 + h*8 + c]; }
            else              { const int j = i - 640; lr = j/24; const int rem = j - lr*24;
                                const int c = rem/3;
                                off = 32 + c*4 + 1 + (rem - c*3);
                                val = v1[(nb0+lr)*192 + h*24 + rem]; }
            sv[lr][off] = val;
        }
        __syncthreads();
        // diag: 16 lanes per row, shuffle reduce
        {
            const int row = tid >> 4, t = tid & 15;
            const float a = sv[row][2*t], b2 = sv[row][2*t+1];
            float ss = a*a + b2*b2;
            ss += __shfl_xor(ss, 1); ss += __shfl_xor(ss, 2);
            ss += __shfl_xor(ss, 4); ss += __shfl_xor(ss, 8);
            if (t == 0) { sdiag[row] = 0.5f*ss; diagg[(nb0+row)*8 + h] = 0.5f*ss; }
        }
        // dd for this half's 8 rows -> ddl (no sdiag dependency here)
#pragma unroll
        for (int r8 = 0; r8 < 8; ++r8) {
            const int row = half*8 + r8;
            const float4* f4 = (const float4*)&sv[row][0];
            float dd = 0.f;
#pragma unroll
            for (int q = 0; q < 8; ++q) {
                const float4 qv = f4[q];
                dd = fmaf(qv.x, wreg[q*4+0], dd);
                dd = fmaf(qv.y, wreg[q*4+1], dd);
                dd = fmaf(qv.z, wreg[q*4+2], dd);
                dd = fmaf(qv.w, wreg[q*4+3], dd);
            }
            ddl[row][m] = dd;
        }
        __syncthreads();
        // accumulate: EVERY thread, ALL 16 rows (kp from LDS dd)
#pragma unroll
        for (int row = 0; row < 16; ++row) {
            const float kp = __expf(ddl[row][m] - sdiag[row]);
            ksum_acc += kp;
            const float4* vv = (const float4*)&sv[row][32];
#pragma unroll
            for (int cc = 0; cc < 4; ++cc) {
                const float4 vq = vv[half*4 + cc];
                acc[cc*4+0] = fmaf(kp, vq.x, acc[cc*4+0]);
                acc[cc*4+1] = fmaf(kp, vq.y, acc[cc*4+1]);
                acc[cc*4+2] = fmaf(kp, vq.z, acc[cc*4+2]);
                acc[cc*4+3] = fmaf(kp, vq.w, acc[cc*4+3]);
            }
        }
        if (tid < 32) {
#pragma unroll
            for (int lr = 0; lr < 16; ++lr) vsum_acc += sv[lr][32 + tid];
        }
        // rowmax over m (for Qp in k3, and gmax)
        if (tid < 128) {
            const int row = tid >> 3, mo = tid & 7;
            float mx = -3.4e38f;
#pragma unroll
            for (int q = 0; q < 4; ++q) {
                const float4 v4 = *(const float4*)&ddl[row][mo*16 + q*4];
                mx = fmaxf(mx, fmaxf(fmaxf(v4.x, v4.y), fmaxf(v4.z, v4.w)));
            }
            mx = fmaxf(mx, __shfl_xor(mx, 1));
            mx = fmaxf(mx, __shfl_xor(mx, 2));
            mx = fmaxf(mx, __shfl_xor(mx, 4));
            if (mo == 0) rmaxg[(nb0+row)*8 + h] = mx;
            blockmax = fmaxf(blockmax, mx);
        }
    }
    float* ctxr = ws + CTXR_OFF;
#pragma unroll
    for (int cc = 0; cc < 4; ++cc) {
        const int c = half*4 + cc;
#pragma unroll
        for (int j = 0; j < 4; ++j)
            atomicAdd(&ctxr[((bh*8 + c)*MM + m)*4 + j], acc[cc*4+j]);
    }
    if (half == 0) atomicAdd(ws + KSUMR_OFF + bh*MM + m, ksum_acc);
    if (tid < 32)  atomicAdd(ws + VSUM_OFF + bh*32 + tid, vsum_acc);
    float bm = blockmax;
#pragma unroll
    for (int off = 32; off; off >>= 1) bm = fmaxf(bm, __shfl_xor(bm, off, 64));
    if ((tid & 63) == 0) bred[tid >> 6] = bm;
    __syncthreads();
    if (tid == 0) {
        const float g = fmaxf(fmaxf(bred[0], bred[1]), fmaxf(bred[2], bred[3]));
        unsigned u = __float_as_uint(g);
        u = (u & 0x80000000u) ? ~u : (u | 0x80000000u);
        atomicMax((unsigned*)(ws + GMAX_OFF), u);
    }
}

// ------- k3: finalize ctx/ksum, Qp from fresh k-gather, D_inv, readout -----
__global__ __launch_bounds__(256) void k_out(const float* __restrict__ kk0,
                                             const float* __restrict__ kk1,
                                             const float* __restrict__ w,
                                             const float* __restrict__ ws,
                                             float* __restrict__ out) {
    __shared__ float ctx_s[8*516];
    __shared__ float qpT[128*68];     // [m][row<64], pad 68 (b128-aligned)
    __shared__ float sf[64][36];      // feats*DN, pad 36 keeps float4 alignment
    __shared__ float sdiag[64], srmax[64], dinv[64], ksl[128];
    const int tid = threadIdx.x;
    const int m = tid & 127, half = tid >> 7;
    float wreg[DDIM];
    {
        const float4* w4 = (const float4*)(w + m*DDIM);
#pragma unroll
        for (int q = 0; q < 8; ++q) {
            const float4 t = w4[q];
            wreg[q*4+0]=t.x; wreg[q*4+1]=t.y; wreg[q*4+2]=t.z; wreg[q*4+3]=t.w;
        }
    }
    const int bh = blockIdx.x >> 6, blk = blockIdx.x & 63;
    const int b = bh >> 3, h = bh & 7;
    const unsigned gu = *((const unsigned*)(ws + GMAX_OFF));
    const float gm = (gu & 0x80000000u) ? __uint_as_float(gu & 0x7fffffffu)
                                        : __uint_as_float(~gu);
    const float alpha = __expf(-gm);
    const float* ctxr = ws + CTXR_OFF + bh*4096;
    const float* vsg  = ws + VSUM_OFF + bh*32;
    for (int g = tid; g < 4096; g += 256) {
        const int c = g >> 9, mm2 = (g >> 2) & 127, j = g & 3;
        ctx_s[c*516 + mm2*4 + j] = RATIO*(alpha*ctxr[g] + EPSF*vsg[c*4 + j]);
    }
    if (tid < 128) ksl[tid] = RATIO*(alpha*ws[KSUMR_OFF + bh*MM + tid] + EPSF*(float)LL);
    const float* rmaxg = ws + RMAX_OFF;
    const float* diagg = ws + DIAG_OFF;
    for (int tile = 0; tile < 2; ++tile) {
        const int lbase = blk*128 + tile*64;
        const int n0 = b*LL + lbase;
        __syncthreads();
        // stage 64 feature rows + diag/rmax
#pragma unroll
        for (int p = 0; p < 8; ++p) {
            const int i = tid + p*256;
            if (i < 512)       { const int lr = i >> 3, d = i & 7;
                                 sf[lr][d] = kk0[(n0+lr)*64 + h*8 + d] * DN; }
            else if (i < 2048) { const int jn = i - 512; const int lr = jn/24;
                                 const int d2 = jn - lr*24;
                                 sf[lr][8 + d2] = kk1[(n0+lr)*192 + h*24 + d2] * DN; }
        }
        if (tid < 64)       sdiag[tid]    = diagg[(n0+tid)*8 + h];
        else if (tid < 128) srmax[tid-64] = rmaxg[(n0+tid-64)*8 + h];
        __syncthreads();
        // phase A: Qp for 64 rows -> qpT
#pragma unroll
        for (int r4 = 0; r4 < 8; ++r4) {
            float q4[4];
#pragma unroll
            for (int k = 0; k < 4; ++k) {
                const int row = half*32 + r4*4 + k;
                const float4* f4 = (const float4*)&sf[row][0];
                float dd = 0.f;
#pragma unroll
                for (int q = 0; q < 8; ++q) {
                    const float4 qv = f4[q];
                    dd = fmaf(qv.x, wreg[q*4+0], dd);
                    dd = fmaf(qv.y, wreg[q*4+1], dd);
                    dd = fmaf(qv.z, wreg[q*4+2], dd);
                    dd = fmaf(qv.w, wreg[q*4+3], dd);
                }
                q4[k] = RATIO*(__expf(dd - sdiag[row] - srmax[row]) + EPSF);
            }
            *(float4*)&qpT[m*68 + half*32 + r4*4] = make_float4(q4[0],q4[1],q4[2],q4[3]);
        }
        __syncthreads();
        // phase B: D_inv
        {
            const int row = tid >> 2, mq = tid & 3;
            float ssum = 0.f;
#pragma unroll
            for (int i = 0; i < 32; ++i) {
                const int mm2 = mq*32 + i;
                ssum = fmaf(qpT[mm2*68 + row], ksl[mm2], ssum);
            }
            ssum += __shfl_xor(ssum, 1);
            ssum += __shfl_xor(ssum, 2);
            if (mq == 0) dinv[row] = 1.f/ssum;
        }
        __syncthreads();
        // phase C: out = (qp . ctx) * dinv, register-tiled
        {
            const int c = tid & 7, mh = (tid >> 3) & 1, rg = tid >> 4;
            float4 a0 = {0,0,0,0}, a1 = {0,0,0,0}, a2 = {0,0,0,0}, a3 = {0,0,0,0};
            const float4* cx = (const float4*)&ctx_s[c*516];
            const int mstart = mh*64;
#pragma unroll 8
            for (int i = 0; i < 64; ++i) {
                const int mm2 = mstart + i;
                const float4 cv = cx[mm2];
                const float4 qv = *(const float4*)&qpT[mm2*68 + rg*4];
                a0.x = fmaf(qv.x, cv.x, a0.x); a0.y = fmaf(qv.x, cv.y, a0.y);
                a0.z = fmaf(qv.x, cv.z, a0.z); a0.w = fmaf(qv.x, cv.w, a0.w);
                a1.x = fmaf(qv.y, cv.x, a1.x); a1.y = fmaf(qv.y, cv.y, a1.y);
                a1.z = fmaf(qv.y, cv.z, a1.z); a1.w = fmaf(qv.y, cv.w, a1.w);
                a2.x = fmaf(qv.z, cv.x, a2.x); a2.y = fmaf(qv.z, cv.y, a2.y);
                a2.z = fmaf(qv.z, cv.z, a2.z); a2.w = fmaf(qv.z, cv.w, a2.w);
                a3.x = fmaf(qv.w, cv.x, a3.x); a3.y = fmaf(qv.w, cv.y, a3.y);
                a3.z = fmaf(qv.w, cv.z, a3.z); a3.w = fmaf(qv.w, cv.w, a3.w);
            }
            a0.x += __shfl_xor(a0.x, 8); a0.y += __shfl_xor(a0.y, 8);
            a0.z += __shfl_xor(a0.z, 8); a0.w += __shfl_xor(a0.w, 8);
            a1.x += __shfl_xor(a1.x, 8); a1.y += __shfl_xor(a1.y, 8);
            a1.z += __shfl_xor(a1.z, 8); a1.w += __shfl_xor(a1.w, 8);
            a2.x += __shfl_xor(a2.x, 8); a2.y += __shfl_xor(a2.y, 8);
            a2.z += __shfl_xor(a2.z, 8); a2.w += __shfl_xor(a2.w, 8);
            a3.x += __shfl_xor(a3.x, 8); a3.y += __shfl_xor(a3.y, 8);
            a3.z += __shfl_xor(a3.z, 8); a3.w += __shfl_xor(a3.w, 8);
            const float4 s0 = mh ? a2 : a0;
            const float4 s1 = mh ? a3 : a1;
            const int lr0 = rg*4 + mh*2;
#pragma unroll
            for (int k = 0; k < 2; ++k) {
                const float4 sv4 = k ? s1 : s0;
                const int lr = lr0 + k;
                const float dv = dinv[lr];
                const int n = n0 + lr;
                const int base = n*64 + h*8 + c;
                out[base] = sv4.x * dv;
                float* o1 = out + NN*64 + base*3;
                o1[0] = sv4.y * dv;
                o1[1] = sv4.z * dv;
                o1[2] = sv4.w * dv;
            }
        }
    }
}

extern "C" void kernel_launch(void* const* d_in, const int* in_sizes, int n_in,
                              void* d_out, int out_size, void* d_ws, size_t ws_size,
                              hipStream_t stream) {
    const float* v0 = (const float*)d_in[0];
    const float* v1 = (const float*)d_in[1];
    const float* k0 = (const float*)d_in[2];
    const float* k1 = (const float*)d_in[3];
    const float* w  = (const float*)d_in[6];
    float* out = (float*)d_out;
    float* ws  = (float*)d_ws;
    hipMemsetAsync(ws, 0, (size_t)ZERO_FLOATS*sizeof(float), stream);
    k_ctx1<<<1024, 256, 0, stream>>>(k0, k1, v0, v1, w, ws);
    k_out <<<2048, 256, 0, stream>>>(k0, k1, w, ws, out);
}